// Round 3
// 658.481 us; speedup vs baseline: 1.0096x; 1.0096x over previous
//
#include <hip/hip_runtime.h>
#include <math.h>

#define BATCH 4096
#define KDIM 32000
#define NV4 (KDIM / 4)          // 8000 float4 per row
#define ALPHA_C 0.95
#define TEMPERATURE_C 20.0
#define CORRECT_PROB_C 0.99

typedef float f4 __attribute__((ext_vector_type(4)));

// One block per row. Streaming sumexp + rowsum + label gather.
// 4-deep software-pipelined loads: 4 independent float4 loads (4 KB/wave)
// issued before any exp/accumulate consumes them, so the compiler keeps
// vmcnt>0 loads in flight instead of a 1-deep load->exp->add serial loop.
__global__ __launch_bounds__(256) void row_stats(const float* __restrict__ logits,
                                                 const int* __restrict__ labels,
                                                 float2* __restrict__ rowout) {
    const int row = blockIdx.x;
    const int tid = threadIdx.x;
    const float* rowp = logits + (size_t)row * KDIM;
    const f4* rp = reinterpret_cast<const f4*>(rowp);

    // thread 0 fetches the label logit early (overlaps the streaming loop)
    float xlab = 0.0f;
    if (tid == 0) {
        xlab = rowp[labels[row]];
    }

    // Two accumulator banks (A gets loads a/c, B gets loads b/d) -> no
    // loop-carried chain longer than 2 adds per bank per step, and the 4
    // loads of the next step are independent of everything.
    f4 sA = {0.f, 0.f, 0.f, 0.f};
    f4 sB = {0.f, 0.f, 0.f, 0.f};
    f4 tA = {0.f, 0.f, 0.f, 0.f};
    f4 tB = {0.f, 0.f, 0.f, 0.f};

    // main: 7 steps x (4 loads x 256 threads) = 7168 float4
    int j = tid;
    #pragma unroll
    for (int it = 0; it < 7; ++it) {
        f4 a = rp[j];
        f4 b = rp[j + 256];
        f4 c = rp[j + 512];
        f4 d = rp[j + 768];
        tA += a;
        sA.x += __expf(a.x); sA.y += __expf(a.y); sA.z += __expf(a.z); sA.w += __expf(a.w);
        tB += b;
        sB.x += __expf(b.x); sB.y += __expf(b.y); sB.z += __expf(b.z); sB.w += __expf(b.w);
        tA += c;
        sA.x += __expf(c.x); sA.y += __expf(c.y); sA.z += __expf(c.z); sA.w += __expf(c.w);
        tB += d;
        sB.x += __expf(d.x); sB.y += __expf(d.y); sB.z += __expf(d.z); sB.w += __expf(d.w);
        j += 1024;
    }

    // remainder: indices 7168..7999 = 3 full strides of 256 + 64 (tid<64)
    {
        f4 a = rp[j];
        f4 b = rp[j + 256];
        f4 c = rp[j + 512];
        tA += a;
        sA.x += __expf(a.x); sA.y += __expf(a.y); sA.z += __expf(a.z); sA.w += __expf(a.w);
        tB += b;
        sB.x += __expf(b.x); sB.y += __expf(b.y); sB.z += __expf(b.z); sB.w += __expf(b.w);
        tA += c;
        sA.x += __expf(c.x); sA.y += __expf(c.y); sA.z += __expf(c.z); sA.w += __expf(c.w);
        if (tid < 64) {
            f4 d = rp[j + 768];   // 7936 + tid, covers up to 7999
            tB += d;
            sB.x += __expf(d.x); sB.y += __expf(d.y); sB.z += __expf(d.z); sB.w += __expf(d.w);
        }
    }

    f4 sv = sA + sB;
    f4 tv = tA + tB;
    float s = (sv.x + sv.y) + (sv.z + sv.w);
    float t = (tv.x + tv.y) + (tv.z + tv.w);

    // wave (64-lane) butterfly reduce
    #pragma unroll
    for (int off = 32; off > 0; off >>= 1) {
        s += __shfl_xor(s, off);
        t += __shfl_xor(t, off);
    }

    // cross-wave via LDS (4 waves)
    __shared__ float ss[4], st[4];
    const int wid = tid >> 6;
    const int lane = tid & 63;
    if (lane == 0) { ss[wid] = s; st[wid] = t; }
    __syncthreads();
    if (tid == 0) {
        #pragma unroll
        for (int w = 1; w < 4; ++w) { s += ss[w]; t += st[w]; }
        float lse = __logf(s);
        float lp_lab = xlab - lse;
        float S = t - (float)KDIM * lse;
        rowout[row] = make_float2(lp_lab, S);
    }
}

// Single-block final reduction over rows + closed-form KL constants (double).
__global__ __launch_bounds__(256) void finalize(const float2* __restrict__ rowout,
                                                float* __restrict__ out) {
    const int tid = threadIdx.x;
    double slp = 0.0, sS = 0.0;
    for (int r = tid; r < BATCH; r += 256) {
        float2 v = rowout[r];
        slp += (double)v.x;
        sS  += (double)v.y;
    }
    #pragma unroll
    for (int off = 32; off > 0; off >>= 1) {
        slp += __shfl_xor(slp, off);
        sS  += __shfl_xor(sS, off);
    }
    __shared__ double a[4], b[4];
    const int wid = tid >> 6;
    const int lane = tid & 63;
    if (lane == 0) { a[wid] = slp; b[wid] = sS; }
    __syncthreads();
    if (tid == 0) {
        #pragma unroll
        for (int w = 1; w < 4; ++w) { slp += a[w]; sS += b[w]; }
        const double T = TEMPERATURE_C;
        const double a_on  = CORRECT_PROB_C / T;
        const double a_off = ((1.0 - CORRECT_PROB_C) / (double)(KDIM - 1)) / T;
        const double eon = exp(a_on), eoff = exp(a_off);
        const double denom = eon + (double)(KDIM - 1) * eoff;
        const double ton  = eon / denom;
        const double toff = eoff / denom;
        const double C0 = ton * log(ton) + (double)(KDIM - 1) * toff * log(toff);
        // kl_total = B*C0 - sum_i[(ton-toff)*lp_lab_i + toff*S_i]
        const double kl_total = (double)BATCH * C0 - ((ton - toff) * slp + toff * sS);
        const double kl = kl_total / ((double)BATCH * (double)KDIM);
        const double ce = -slp / (double)BATCH;
        out[0] = (float)((1.0 - ALPHA_C) * ce + ALPHA_C * kl);
    }
}

extern "C" void kernel_launch(void* const* d_in, const int* in_sizes, int n_in,
                              void* d_out, int out_size, void* d_ws, size_t ws_size,
                              hipStream_t stream) {
    const float* logits = (const float*)d_in[0];
    const int*   labels = (const int*)d_in[1];
    float2* rowout = (float2*)d_ws;              // 4096 * 8 B = 32 KB scratch
    float*  out    = (float*)d_out;

    row_stats<<<BATCH, 256, 0, stream>>>(logits, labels, rowout);
    finalize<<<1, 256, 0, stream>>>(rowout, out);
}